// Round 1
// baseline (130.332 us; speedup 1.0000x reference)
//
#include <hip/hip_runtime.h>

// ---------------------------------------------------------------------------
// SgpiSTFT: Hermitian iFFT (as GEMM vs fixed cos/sin matrix) + window + 4-tap
// overlap-add + flip/transpose, fused.
//
// Math:  y[n,t] = Re(c0) + 2*sum_{k=1..255}( Re_k cos(2pi n k/512) + Im_k sin(...) )
//        out[b, t*256 + (255-j)] = 256*( y[256+j,t]  *win[768+j]
//                                       + y[j,  t-1] *win[512+j]
//                                       + y[256+j,t-2]*win[256+j]
//                                       + y[j,  t-3] *win[j] )
// Symmetry: y[n+256] uses (-1)^k weights -> accumulate even-k (E) and odd-k (O)
// partial GEMMs for n in [0,256): y[n]=E+O, y[n+256]=E-O.
// ---------------------------------------------------------------------------

typedef __attribute__((ext_vector_type(8))) short short8;
typedef __attribute__((ext_vector_type(8))) __bf16 bf16x8;
typedef __attribute__((ext_vector_type(4))) float floatx4;

__device__ inline short f2bf(float f) {
  unsigned u = __builtin_bit_cast(unsigned, f);
  u = (u + 0x7fffu + ((u >> 16) & 1u)) >> 16;
  return (short)(unsigned short)u;
}

#define PI_OVER_256 0.01227184630308513f

// M matrix, 256 rows (n) x 512 cols (kappa), kappa = column-permuted k:
//   kappa < 256: gk = 2*kappa      (even k)
//   kappa >=256: gk = 2*(kappa-256)+1 (odd k)
//   M[n][gk] = (gk==0) ? 1 : (gk<256 ? 2cos(2pi n gk/512) : 2sin(2pi n (gk-256)/512))
// Stored pre-swizzled in MFMA A-fragment order:
//   frag idx = (ntile*16 + kstep)*64 + lane ; lane holds row n = ntile*16+(lane&15),
//   kappa = kstep*32 + (lane>>4)*8 + e, e=0..7  -> one dwordx4 per lane.
__global__ void build_m(short* __restrict__ M) {
  int idx = blockIdx.x * blockDim.x + threadIdx.x;  // [0, 16*16*64) = 16384
  int ntile = idx >> 10;
  int s = (idx >> 6) & 15;
  int lane = idx & 63;
  int n = ntile * 16 + (lane & 15);
  int kb = lane >> 4;
  short8 v;
#pragma unroll
  for (int e = 0; e < 8; e++) {
    int kap = s * 32 + kb * 8 + e;
    int gk = 2 * (kap & 255) + (kap >> 8);
    float val;
    if (gk == 0) {
      val = 1.0f;
    } else if (gk < 256) {
      int m = (n * gk) & 511;
      val = 2.0f * __cosf((float)m * PI_OVER_256);
    } else {
      int m = (n * (gk - 256)) & 511;
      val = 2.0f * __sinf((float)m * PI_OVER_256);
    }
    v[e] = f2bf(val);
  }
  ((short8*)M)[idx] = v;
}

// Block: one batch b, X columns [c0, c0+64), c0 = 61*tile - 3 (3-col halo, cols
// outside [0,4000) zero-padded == dropped OLA taps). Outputs t in [c0+3, c0+64)
// clamped to [0,3999). 512 threads = 8 waves; wave w owns output rows
// j in [32*w, 32*w+32) (n-tiles 2w, 2w+1) for both E and O accumulators.
__global__ __launch_bounds__(512) void gemm_ola(
    const float* __restrict__ in, const float* __restrict__ win,
    const short* __restrict__ M, float* __restrict__ out) {
  // X tile in LDS: bf16, column-major [col][kappa], kappa-groups of 8 XOR-swizzled
  // by (col&7) so B-fragment ds_read_b128 is ~conflict-free.
  __shared__ short ldsX[64 * 512];  // 64 KiB

  const int tid = threadIdx.x;
  const int b = blockIdx.y;
  const int tile = blockIdx.x;
  const int c0 = 61 * tile - 3;

  // ---- stage X: fp32 global -> bf16 LDS (row-permute + transpose) ----
  {
    const int col = tid & 63;   // local column; wave covers 64 consecutive cols
    const int kc = tid >> 6;    // kappa chunk of 64
    const int gc = c0 + col;
    const bool valid = (gc >= 0) & (gc < 4000);
    const float* src = in + (size_t)b * 514 * 4000 + gc;
#pragma unroll
    for (int i0 = 0; i0 < 64; i0 += 8) {
      short8 v;
#pragma unroll
      for (int j = 0; j < 8; j++) {
        int kap = kc * 64 + i0 + j;
        int gk = 2 * (kap & 255) + (kap >> 8);
        int row = (gk < 256) ? gk : gk + 1;  // imag rows start at 257
        float f = valid ? src[(size_t)row * 4000] : 0.0f;
        v[j] = f2bf(f);
      }
      int g = (kc * 64 + i0) >> 3;
      *(short8*)&ldsX[col * 512 + ((g ^ (col & 7)) << 3)] = v;
    }
  }
  __syncthreads();

  // ---- GEMM: accE (kappa<256, even k), accO (kappa>=256, odd k) ----
  const int w = tid >> 6;
  const int lane = tid & 63;
  const int c = lane & 15;   // MFMA col (t within 16-tile)
  const int kb = lane >> 4;  // MFMA k-block / C row-group

  floatx4 accE[2][4] = {};
  floatx4 accO[2][4] = {};

  const short8* Mf = (const short8*)M;
  const int nt0 = 2 * w, nt1 = 2 * w + 1;

#pragma unroll
  for (int s = 0; s < 16; s++) {
    bf16x8 a0 = __builtin_bit_cast(bf16x8, Mf[(nt0 * 16 + s) * 64 + lane]);
    bf16x8 a1 = __builtin_bit_cast(bf16x8, Mf[(nt1 * 16 + s) * 64 + lane]);
    bf16x8 bq[4];
    const int g = 4 * s + kb;
#pragma unroll
    for (int q = 0; q < 4; q++) {
      int col = 16 * q + c;
      bq[q] = __builtin_bit_cast(
          bf16x8, *(const short8*)&ldsX[col * 512 + ((g ^ (col & 7)) << 3)]);
    }
#pragma unroll
    for (int q = 0; q < 4; q++) {
      if (s < 8) {
        accE[0][q] = __builtin_amdgcn_mfma_f32_16x16x32_bf16(a0, bq[q], accE[0][q], 0, 0, 0);
        accE[1][q] = __builtin_amdgcn_mfma_f32_16x16x32_bf16(a1, bq[q], accE[1][q], 0, 0, 0);
      } else {
        accO[0][q] = __builtin_amdgcn_mfma_f32_16x16x32_bf16(a0, bq[q], accO[0][q], 0, 0, 0);
        accO[1][q] = __builtin_amdgcn_mfma_f32_16x16x32_bf16(a1, bq[q], accO[1][q], 0, 0, 0);
      }
    }
  }

  // recombine in place: accE := Y = E+O (rows j), accO := Yh = E-O (rows 256+j)
#pragma unroll
  for (int jt = 0; jt < 2; jt++)
#pragma unroll
    for (int q = 0; q < 4; q++) {
      floatx4 e = accE[jt][q], o = accO[jt][q];
      accE[jt][q] = e + o;
      accO[jt][q] = e - o;
    }

  // ---- OLA epilogue: taps at t-1..t-3 via in-wave shuffles ----
  // C-layout: col = lane&15, row = (lane>>4)*4 + reg.
  const int rg = lane >> 4;
#pragma unroll
  for (int jt = 0; jt < 2; jt++) {
    const int j0 = 32 * w + 16 * jt;
    const int jr = j0 + rg * 4;  // this lane's 4 consecutive j rows
    const floatx4 w0   = *(const floatx4*)&win[jr];
    const floatx4 w256 = *(const floatx4*)&win[256 + jr];
    const floatx4 w512 = *(const floatx4*)&win[512 + jr];
    const floatx4 w768 = *(const floatx4*)&win[768 + jr];
#pragma unroll
    for (int q = 0; q < 4; q++) {
      const int qm = (q > 0) ? (q - 1) : 0;
      floatx4 y1, yh2, y3;
#pragma unroll
      for (int p = 0; p < 4; p++) {
        // shift s: value at col c-s; cross into tile q-1 when c<s
        float a1 = __shfl(accE[jt][q][p], lane - 1, 64);
        float b1 = (q > 0) ? __shfl(accE[jt][qm][p], lane + 15, 64) : 0.0f;
        y1[p] = (c >= 1) ? a1 : b1;
        float a2 = __shfl(accO[jt][q][p], lane - 2, 64);
        float b2 = (q > 0) ? __shfl(accO[jt][qm][p], lane + 14, 64) : 0.0f;
        yh2[p] = (c >= 2) ? a2 : b2;
        float a3 = __shfl(accE[jt][q][p], lane - 3, 64);
        float b3 = (q > 0) ? __shfl(accE[jt][qm][p], lane + 13, 64) : 0.0f;
        y3[p] = (c >= 3) ? a3 : b3;
      }
      const int t = c0 + 16 * q + c;
      if ((16 * q + c) >= 3 && t <= 3998) {
        floatx4 v = accO[jt][q] * w768 + y1 * w512 + yh2 * w256 + y3 * w0;
        v = v * 256.0f;
        // out index i = 255 - j ; lane's rows are jr..jr+3 -> reversed float4
        floatx4 o;
        o[0] = v[3]; o[1] = v[2]; o[2] = v[1]; o[3] = v[0];
        const int ibase = 252 - j0 - 4 * rg;
        *(floatx4*)&out[((size_t)b * 3999 + t) * 256 + ibase] = o;
      }
    }
  }
}

extern "C" void kernel_launch(void* const* d_in, const int* in_sizes, int n_in,
                              void* d_out, int out_size, void* d_ws, size_t ws_size,
                              hipStream_t stream) {
  const float* in = (const float*)d_in[0];   // (8, 514, 4000) fp32
  const float* win = (const float*)d_in[1];  // (1024,) fp32
  float* out = (float*)d_out;                // (8, 3999*256) fp32
  short* M = (short*)d_ws;                   // 256 KiB bf16 coefficient matrix

  hipLaunchKernelGGL(build_m, dim3(64), dim3(256), 0, stream, M);
  hipLaunchKernelGGL(gemm_ola, dim3(66, 8), dim3(512), 0, stream, in, win, M, out);
}

// Round 2
// 120.916 us; speedup vs baseline: 1.0779x; 1.0779x over previous
//
#include <hip/hip_runtime.h>

// ---------------------------------------------------------------------------
// SgpiSTFT: Hermitian iFFT (as GEMM vs fixed cos/sin matrix) + window + 4-tap
// overlap-add + flip/transpose, fused.
//
//   y[n,t] = Re(c0) + 2*sum_{k=1..255}( Re_k cos(2pi n k/512) + Im_k sin(...) )
//   out[b, t*256 + (255-j)] = 256*( y[256+j,t]  *win[768+j]
//                                  + y[j,  t-1] *win[512+j]
//                                  + y[256+j,t-2]*win[256+j]
//                                  + y[j,  t-3] *win[j] )
// Symmetry: y[256+j] flips sign of odd-k terms -> accumulate even-k (E) and
// odd-k (O) halves; Y=E+O, Yh=E-O.
//
// Round-2 structure: MFMA operands SWAPPED vs round 1 (A = X from LDS with
// m=t, B = M from global with n=j). C-tile rows (reg axis) = t, so the OLA
// taps t-1..t-3 are register shifts + one lane-16 shuffle at group edges.
// 32-col blocks (32 KiB LDS), dwordx4 staging with register transpose,
// depth-1 prefetch on M loads.
// ---------------------------------------------------------------------------

typedef __attribute__((ext_vector_type(8))) short short8;
typedef __attribute__((ext_vector_type(8))) __bf16 bf16x8;
typedef __attribute__((ext_vector_type(4))) float floatx4;

__device__ inline short f2bf(float f) {
  unsigned u = __builtin_bit_cast(unsigned, f);
  u = (u + 0x7fffu + ((u >> 16) & 1u)) >> 16;
  return (short)(unsigned short)u;
}

#define PI_OVER_256 0.01227184630308513f

// M matrix in MFMA fragment order, identical to round 1 (validated):
//   frag idx = (Jtile*16 + s)*64 + lane ; lane holds row j = Jtile*16+(lane&15),
//   kappa = s*32 + (lane>>4)*8 + e, e=0..7 (one short8 per lane).
//   kappa < 256: gk = 2*kappa (even);  kappa >= 256: gk = 2*(kappa-256)+1 (odd)
//   M[j][gk] = (gk==0) ? 1 : (gk<256 ? 2cos(2pi j gk/512) : 2sin(2pi j (gk-256)/512))
__global__ void build_m(short* __restrict__ M) {
  int idx = blockIdx.x * blockDim.x + threadIdx.x;  // [0, 16*16*64)
  int ntile = idx >> 10;
  int s = (idx >> 6) & 15;
  int lane = idx & 63;
  int n = ntile * 16 + (lane & 15);
  int kb = lane >> 4;
  short8 v;
#pragma unroll
  for (int e = 0; e < 8; e++) {
    int kap = s * 32 + kb * 8 + e;
    int gk = 2 * (kap & 255) + (kap >> 8);
    float val;
    if (gk == 0) {
      val = 1.0f;
    } else if (gk < 256) {
      int m = (n * gk) & 511;
      val = 2.0f * __cosf((float)m * PI_OVER_256);
    } else {
      int m = (n * (gk - 256)) & 511;
      val = 2.0f * __sinf((float)m * PI_OVER_256);
    }
    v[e] = f2bf(val);
  }
  ((short8*)M)[idx] = v;
}

// Block: batch b, X columns [c0, c0+32), c0 = 28*tile - 4 (halo 4, 16B-aligned
// global loads). Outputs local L in [4,32) -> t = c0+L, masked to t <= 3998.
// 512 threads = 8 waves; wave w owns j-tiles {2w, 2w+1} (j rows 32w..32w+31)
// for ALL 32 t-columns.
__global__ __launch_bounds__(512) void gemm_ola(
    const float* __restrict__ in, const float* __restrict__ win,
    const short* __restrict__ M, float* __restrict__ out) {
  // X tile, bf16, column-major [col][kappa], kappa groups of 8 XOR-swizzled by
  // (col&7) -> conflict-tolerable b128 reads/writes.
  __shared__ short ldsX[32 * 512];  // 32 KiB

  const int tid = threadIdx.x;
  const int b = blockIdx.y;
  const int tile = blockIdx.x;
  const int c0 = 28 * tile - 4;

  // ---- stage X: dwordx4 global loads + register transpose -> bf16 LDS ----
  {
    const int cbase = 4 * (tid & 7);     // 4 consecutive cols
    const int kap0 = (tid >> 3) * 8;     // 8 consecutive kappa
    const int gc = c0 + cbase;
    floatx4 f[8];
    if (gc >= 0 && gc <= 3996) {
      const float* src = in + (size_t)b * 2056000 + gc;
#pragma unroll
      for (int j = 0; j < 8; j++) {
        int kap = kap0 + j;
        int gk = 2 * (kap & 255) + (kap >> 8);
        int row = (gk < 256) ? gk : gk + 1;  // imag rows start at 257
        f[j] = *(const floatx4*)(src + (size_t)row * 4000);
      }
    } else {
#pragma unroll
      for (int j = 0; j < 8; j++) f[j] = floatx4{0.f, 0.f, 0.f, 0.f};
    }
    const int g = kap0 >> 3;  // kappa-group, 8-aligned
#pragma unroll
    for (int cc = 0; cc < 4; cc++) {
      short8 v;
#pragma unroll
      for (int j = 0; j < 8; j++) v[j] = f2bf(f[j][cc]);
      const int col = cbase + cc;
      *(short8*)&ldsX[col * 512 + ((g ^ (col & 7)) << 3)] = v;
    }
  }
  __syncthreads();

  const int w = tid >> 6;
  const int lane = tid & 63;
  const int c = lane & 15;   // MFMA spatial index within 16-tile
  const int kb = lane >> 4;  // k-block; also C row-group rg
  const int rg = kb;

  // acc[q][jt]: q = t-tile (rows of C), jt = j-tile (cols of C)
  floatx4 accE[2][2] = {};
  floatx4 accO[2][2] = {};

  const short8* Mf = (const short8*)M;
  const int J0 = 2 * w, J1 = 2 * w + 1;

  bf16x8 cb0 = __builtin_bit_cast(bf16x8, Mf[(J0 * 16 + 0) * 64 + lane]);
  bf16x8 cb1 = __builtin_bit_cast(bf16x8, Mf[(J1 * 16 + 0) * 64 + lane]);

#pragma unroll
  for (int s = 0; s < 16; s++) {
    // prefetch next-s M fragments (L2) before touching this step's MFMAs
    bf16x8 nb0, nb1;
    if (s < 15) {
      nb0 = __builtin_bit_cast(bf16x8, Mf[(J0 * 16 + s + 1) * 64 + lane]);
      nb1 = __builtin_bit_cast(bf16x8, Mf[(J1 * 16 + s + 1) * 64 + lane]);
    }
    // A fragments (X) from LDS: lane m = t-col
    const int g = 4 * s + kb;
    const int col0 = c;
    const int col1 = 16 + c;
    bf16x8 a0 = __builtin_bit_cast(
        bf16x8, *(const short8*)&ldsX[col0 * 512 + ((g ^ (col0 & 7)) << 3)]);
    bf16x8 a1 = __builtin_bit_cast(
        bf16x8, *(const short8*)&ldsX[col1 * 512 + ((g ^ (col1 & 7)) << 3)]);
    if (s < 8) {
      accE[0][0] = __builtin_amdgcn_mfma_f32_16x16x32_bf16(a0, cb0, accE[0][0], 0, 0, 0);
      accE[0][1] = __builtin_amdgcn_mfma_f32_16x16x32_bf16(a0, cb1, accE[0][1], 0, 0, 0);
      accE[1][0] = __builtin_amdgcn_mfma_f32_16x16x32_bf16(a1, cb0, accE[1][0], 0, 0, 0);
      accE[1][1] = __builtin_amdgcn_mfma_f32_16x16x32_bf16(a1, cb1, accE[1][1], 0, 0, 0);
    } else {
      accO[0][0] = __builtin_amdgcn_mfma_f32_16x16x32_bf16(a0, cb0, accO[0][0], 0, 0, 0);
      accO[0][1] = __builtin_amdgcn_mfma_f32_16x16x32_bf16(a0, cb1, accO[0][1], 0, 0, 0);
      accO[1][0] = __builtin_amdgcn_mfma_f32_16x16x32_bf16(a1, cb0, accO[1][0], 0, 0, 0);
      accO[1][1] = __builtin_amdgcn_mfma_f32_16x16x32_bf16(a1, cb1, accO[1][1], 0, 0, 0);
    }
    if (s < 15) { cb0 = nb0; cb1 = nb1; }
  }

  // ---- OLA epilogue ----
  // C layout: col (lane&15) = j within j-tile; row (rg*4+p) = local t offset.
  // Tap t-d = reg p-d; p-d<0 pulls reg p-d+4 from the row-group below
  // (lane-16, same q-tile) or, for rg==0, from rg=3 of tile q-1 (lane+48).
#pragma unroll
  for (int jt = 0; jt < 2; jt++) {
    const int J = 2 * w + jt;
    const int j = 16 * J + c;
    const float wv0 = 256.0f * win[768 + j];
    const float wv1 = 256.0f * win[512 + j];
    const float wv2 = 256.0f * win[256 + j];
    const float wv3 = 256.0f * win[j];

    floatx4 Y[2], Yh[2];
#pragma unroll
    for (int q = 0; q < 2; q++) {
      Y[q] = accE[q][jt] + accO[q][jt];
      Yh[q] = accE[q][jt] - accO[q][jt];
    }

#pragma unroll
    for (int q = 0; q < 2; q++) {
      const int qm = (q > 0) ? q - 1 : 0;  // q==0 edge is masked (L<4)
      float yb[4], yhb[4];
#pragma unroll
      for (int p = 1; p < 4; p++) {
        float ia = __shfl(Y[q][p], lane - 16, 64);
        float pa = __shfl(Y[qm][p], lane + 48, 64);
        yb[p] = (rg > 0) ? ia : pa;
      }
#pragma unroll
      for (int p = 2; p < 4; p++) {
        float ia = __shfl(Yh[q][p], lane - 16, 64);
        float pa = __shfl(Yh[qm][p], lane + 48, 64);
        yhb[p] = (rg > 0) ? ia : pa;
      }
      floatx4 v;
#pragma unroll
      for (int p = 0; p < 4; p++) {
        float t1 = (p >= 1) ? Y[q][p - 1] : yb[3];
        float t2 = (p >= 2) ? Yh[q][p - 2] : yhb[p + 2];
        float t3 = (p >= 3) ? Y[q][p - 3] : yb[p + 1];
        v[p] = wv0 * Yh[q][p] + wv1 * t1 + wv2 * t2 + wv3 * t3;
      }
#pragma unroll
      for (int p = 0; p < 4; p++) {
        const int L = 16 * q + 4 * rg + p;
        const int t = c0 + L;
        if (L >= 4 && t <= 3998) {
          out[((size_t)b * 3999 + t) * 256 + (255 - j)] = v[p];
        }
      }
    }
  }
}

extern "C" void kernel_launch(void* const* d_in, const int* in_sizes, int n_in,
                              void* d_out, int out_size, void* d_ws, size_t ws_size,
                              hipStream_t stream) {
  const float* in = (const float*)d_in[0];   // (8, 514, 4000) fp32
  const float* win = (const float*)d_in[1];  // (1024,) fp32
  float* out = (float*)d_out;                // (8, 3999*256) fp32
  short* M = (short*)d_ws;                   // 256 KiB bf16 coefficient matrix

  hipLaunchKernelGGL(build_m, dim3(64), dim3(256), 0, stream, M);
  hipLaunchKernelGGL(gemm_ola, dim3(143, 8), dim3(512), 0, stream, in, win, M, out);
}